// Round 2
// baseline (805.553 us; speedup 1.0000x reference)
//
#include <hip/hip_runtime.h>

#define LAT 128

// ---------------- projection GEMM: per 64-node tile, compute Q|K|V x 128 cols ----
// embeds tile staged ONCE; loop 3 mats x 2 col-halves x 2 k-tiles of W staging.
// Q -> Cq (= d_out, stashed); K,V -> interleaved KV[n][256] (K row | V row).
__global__ __launch_bounds__(256) void proj_kernel(
    const float* __restrict__ A,
    const float* __restrict__ Wq, const float* __restrict__ Wk, const float* __restrict__ Wv,
    float* __restrict__ Cq, float* __restrict__ Ckv,
    int N)
{
  __shared__ float eL[64][132];   // 64 nodes x 128 k (+4 pad)
  __shared__ float wL[64][68];    // 64 k x 64 cols (+4 pad)
  const int t = threadIdx.x;
  const int n0 = blockIdx.x * 64;

  // stage embeds tile 64x128 (coalesced float4) -- once per block
  #pragma unroll
  for (int it = 0; it < 8; ++it) {
    int flat = (it * 256 + t) * 4;
    int n = flat >> 7, kk = flat & 127;
    float4 v = make_float4(0.f, 0.f, 0.f, 0.f);
    if (n0 + n < N) v = *(const float4*)(A + (size_t)(n0 + n) * LAT + kk);
    *(float4*)&eL[n][kk] = v;
  }

  const int nl = t & 15;          // node lane: nodes nl, nl+16, nl+32, nl+48
  const int j0 = (t >> 4) * 4;    // 4 consecutive cols

  for (int mat = 0; mat < 3; ++mat) {
    const float* W = (mat == 0) ? Wq : (mat == 1) ? Wk : Wv;
    for (int half = 0; half < 2; ++half) {
      float acc[4][4] = {};
      for (int kt = 0; kt < 2; ++kt) {
        __syncthreads();  // protects eL on first pass, wL reuse afterwards
        #pragma unroll
        for (int it = 0; it < 4; ++it) {
          int flat = (it * 256 + t) * 4;
          int kk = flat >> 6, c = flat & 63;
          *(float4*)&wL[kk][c] =
              *(const float4*)(W + (size_t)(kt * 64 + kk) * LAT + half * 64 + c);
        }
        __syncthreads();
        #pragma unroll 8
        for (int kk = 0; kk < 64; kk += 2) {
          float4 w0 = *(float4*)&wL[kk][j0];
          float4 w1 = *(float4*)&wL[kk + 1][j0];
          #pragma unroll
          for (int i = 0; i < 4; ++i) {
            float2 e = *(float2*)&eL[nl + 16 * i][kt * 64 + kk];
            acc[i][0] += e.x * w0.x + e.y * w1.x;
            acc[i][1] += e.x * w0.y + e.y * w1.y;
            acc[i][2] += e.x * w0.z + e.y * w1.z;
            acc[i][3] += e.x * w0.w + e.y * w1.w;
          }
        }
      }
      #pragma unroll
      for (int i = 0; i < 4; ++i) {
        int n = n0 + nl + 16 * i;
        if (n < N) {
          float4 o = make_float4(acc[i][0], acc[i][1], acc[i][2], acc[i][3]);
          if (mat == 0)
            *(float4*)(Cq + (size_t)n * LAT + half * 64 + j0) = o;
          else
            *(float4*)(Ckv + (size_t)n * 256 + (mat == 2 ? 128 : 0) + half * 64 + j0) = o;
        }
      }
    }
  }
}

// ---------------- CSR build ----------------
__global__ __launch_bounds__(256) void deg_kernel(const int* __restrict__ rows,
                                                  int* __restrict__ counts, int E) {
  int i = blockIdx.x * 256 + threadIdx.x;
  if (i < E) atomicAdd(&counts[rows[i]], 1);
}

__global__ __launch_bounds__(1024) void scan1_kernel(const int* __restrict__ counts,
                                                     int* __restrict__ starts,
                                                     int* __restrict__ bsums, int N) {
  __shared__ int sh[1024];
  int t = threadIdx.x;
  int i = blockIdx.x * 1024 + t;
  int v = (i < N) ? counts[i] : 0;
  sh[t] = v; __syncthreads();
  for (int off = 1; off < 1024; off <<= 1) {
    int x = (t >= off) ? sh[t - off] : 0;
    __syncthreads();
    sh[t] += x;
    __syncthreads();
  }
  if (i < N) starts[i] = sh[t] - v;           // block-local exclusive
  if (t == 1023) bsums[blockIdx.x] = sh[t];   // block total
}

__global__ __launch_bounds__(1024) void scan2_kernel(int* __restrict__ bsums, int nb) {
  __shared__ int sh[1024];
  int t = threadIdx.x;
  int v = (t < nb) ? bsums[t] : 0;
  sh[t] = v; __syncthreads();
  for (int off = 1; off < 1024; off <<= 1) {
    int x = (t >= off) ? sh[t - off] : 0;
    __syncthreads();
    sh[t] += x;
    __syncthreads();
  }
  if (t < nb) bsums[t] = sh[t] - v;           // exclusive
}

__global__ __launch_bounds__(256) void scan3_kernel(int* __restrict__ starts,
                                                    const int* __restrict__ bsums,
                                                    int* __restrict__ cursor, int N) {
  int i = blockIdx.x * 256 + threadIdx.x;
  if (i < N) {
    int s = starts[i] + bsums[i >> 10];
    starts[i] = s;
    cursor[i] = s;
  }
}

__global__ __launch_bounds__(256) void fill_kernel(const int* __restrict__ rows,
                                                   const int* __restrict__ cols,
                                                   int* __restrict__ cursor,
                                                   int* __restrict__ eidx,
                                                   int* __restrict__ ecol, int E) {
  int i = blockIdx.x * 256 + threadIdx.x;
  if (i < E) {
    int p = atomicAdd(&cursor[rows[i]], 1);
    eidx[p] = i;
    ecol[p] = cols[i];
  }
}

// ---------------- fused attention: one wave per node, 4 edges per wave-step ----
// lane = (s,g): s=lane>>4 edge slot, g=lane&15 owns dims g*8..g*8+7 (head g>>2).
// Per step: 4 edges in parallel; per-head dot = 8 MAC + 2 shfl_xor.
// Single pass: accumulate denom and unnormalized sum(ea*v); write ea to outAtt;
// scale everything by rden at the end (outAtt scaled by norm_kernel).
__global__ __launch_bounds__(256) void attn_kernel(
    const float* __restrict__ KV,
    const int* __restrict__ starts, const int* __restrict__ counts,
    const int* __restrict__ eidx, const int* __restrict__ ecol,
    float* __restrict__ outRes,    // in: Q rows (stashed); out: result
    float* __restrict__ outAtt,    // unnormalized exp(att)
    float* __restrict__ rdenArr,   // [N][4]
    int N)
{
  const int w = threadIdx.x >> 6;
  const int lane = threadIdx.x & 63;
  const int n = blockIdx.x * 4 + w;
  if (n >= N) return;
  const int g = lane & 15;
  const int s = lane >> 4;
  const int start = starts[n];
  const int deg = counts[n];

  const float4 q0 = *(const float4*)(outRes + (size_t)n * LAT + g * 8);
  const float4 q1 = *(const float4*)(outRes + (size_t)n * LAT + g * 8 + 4);

  float denom = 0.f;
  float acc[8] = {};
  for (int base = 0; base < deg; base += 64) {
    int j = base + lane;
    int c_l = 0, e_l = 0;
    if (j < deg) { c_l = ecol[start + j]; e_l = eidx[start + j]; }
    int m = deg - base; if (m > 64) m = 64;
    int steps = (m + 3) >> 2;
    #pragma unroll 2
    for (int st = 0; st < steps; ++st) {
      int jj = st * 4 + s;                 // my slot's edge within this chunk
      int c = __shfl(c_l, jj);
      int e = __shfl(e_l, jj);
      bool valid = (jj < m);
      const float* kv = KV + (size_t)c * 256;
      float4 k0 = *(const float4*)(kv + g * 8);
      float4 k1 = *(const float4*)(kv + g * 8 + 4);
      float4 v0 = *(const float4*)(kv + 128 + g * 8);
      float4 v1 = *(const float4*)(kv + 128 + g * 8 + 4);
      float p = q0.x * k0.x + q0.y * k0.y + q0.z * k0.z + q0.w * k0.w
              + q1.x * k1.x + q1.y * k1.y + q1.z * k1.z + q1.w * k1.w;
      p += __shfl_xor(p, 1);
      p += __shfl_xor(p, 2);               // all 4 lanes of the head-group have the dot
      p = fminf(fmaxf(p, -10.f), 10.f);
      float ea = valid ? __expf(p) : 0.f;
      denom += ea;
      acc[0] += ea * v0.x; acc[1] += ea * v0.y; acc[2] += ea * v0.z; acc[3] += ea * v0.w;
      acc[4] += ea * v1.x; acc[5] += ea * v1.y; acc[6] += ea * v1.z; acc[7] += ea * v1.w;
      if (valid && (g & 3) == 0) outAtt[(size_t)e * 4 + (g >> 2)] = ea;
    }
  }
  // cross-slot reduction (bits 4,5)
  denom += __shfl_xor(denom, 16);
  denom += __shfl_xor(denom, 32);
  #pragma unroll
  for (int i = 0; i < 8; ++i) {
    acc[i] += __shfl_xor(acc[i], 16);
    acc[i] += __shfl_xor(acc[i], 32);
  }
  float rden = 1.f / (denom + 1e-8f);
  if (lane < 16) {
    if ((g & 3) == 0) rdenArr[(size_t)n * 4 + (g >> 2)] = rden;
    float4 r0 = make_float4(acc[0] * rden, acc[1] * rden, acc[2] * rden, acc[3] * rden);
    float4 r1 = make_float4(acc[4] * rden, acc[5] * rden, acc[6] * rden, acc[7] * rden);
    *(float4*)(outRes + (size_t)n * LAT + g * 8) = r0;
    *(float4*)(outRes + (size_t)n * LAT + g * 8 + 4) = r1;
  }
}

// ---------------- normalize att output (edge-parallel) ----------------
__global__ __launch_bounds__(256) void norm_kernel(const int* __restrict__ rows,
                                                   const float* __restrict__ rdenArr,
                                                   float* __restrict__ outAtt, int E) {
  int e = blockIdx.x * 256 + threadIdx.x;
  if (e < E) {
    float4 a = *(float4*)(outAtt + (size_t)e * 4);
    int r = rows[e];
    float4 d = *(const float4*)(rdenArr + (size_t)r * 4);
    a.x *= d.x; a.y *= d.y; a.z *= d.z; a.w *= d.w;
    *(float4*)(outAtt + (size_t)e * 4) = a;
  }
}

// ---------------- launch ----------------
extern "C" void kernel_launch(void* const* d_in, const int* in_sizes, int n_in,
                              void* d_out, int out_size, void* d_ws, size_t ws_size,
                              hipStream_t stream) {
  const float* embeds = (const float*)d_in[0];
  const float* qT = (const float*)d_in[1];
  const float* kT = (const float*)d_in[2];
  const float* vT = (const float*)d_in[3];
  const int* rows = (const int*)d_in[4];
  const int* cols = (const int*)d_in[5];

  if (in_sizes[1] != LAT * LAT) return;   // kernel specialized for latdim=128
  const int N = in_sizes[0] / LAT;
  const int E = in_sizes[4];

  float* outRes = (float*)d_out;                    // [N,128]; temporarily holds Q
  float* outAtt = outRes + (size_t)N * LAT;         // [E,4]

  // workspace carve-up
  char* w = (char*)d_ws;
  size_t need = (size_t)N * 256 * 4 + (size_t)N * 4 * 3 + 1024 * 4
              + (size_t)E * 4 * 2 + (size_t)N * 4 * 4;
  if (ws_size < need) return;                       // loud failure > silent corruption
  float* KV = (float*)w;      w += (size_t)N * 256 * 4;   // K|V interleaved rows
  int* counts = (int*)w;      w += (size_t)N * 4;
  int* starts = (int*)w;      w += (size_t)N * 4;
  int* cursor = (int*)w;      w += (size_t)N * 4;
  int* bsums  = (int*)w;      w += 1024 * 4;
  int* eidx   = (int*)w;      w += (size_t)E * 4;
  int* ecol   = (int*)w;      w += (size_t)E * 4;
  float* rdenArr = (float*)w; w += (size_t)N * 4 * 4;

  hipMemsetAsync(counts, 0, (size_t)N * 4, stream);

  // per-node projections: Q -> outRes (stash), K|V -> interleaved workspace
  proj_kernel<<<(N + 63) / 64, 256, 0, stream>>>(embeds, qT, kT, vT, outRes, KV, N);

  // CSR of edges bucketed by destination (rows)
  deg_kernel<<<(E + 255) / 256, 256, 0, stream>>>(rows, counts, E);
  int nb = (N + 1023) / 1024;
  scan1_kernel<<<nb, 1024, 0, stream>>>(counts, starts, bsums, N);
  scan2_kernel<<<1, 1024, 0, stream>>>(bsums, nb);
  scan3_kernel<<<(N + 255) / 256, 256, 0, stream>>>(starts, bsums, cursor, N);
  fill_kernel<<<(E + 255) / 256, 256, 0, stream>>>(rows, cols, cursor, eidx, ecol, E);

  // fused single-pass attention + aggregation (no atomics)
  attn_kernel<<<(N + 3) / 4, 256, 0, stream>>>(KV, starts, counts, eidx, ecol,
                                               outRes, outAtt, rdenArr, N);
  // scale att output by per-(node,head) denominator
  norm_kernel<<<(E + 255) / 256, 256, 0, stream>>>(rows, rdenArr, outAtt, E);
}

// Round 4
// 695.727 us; speedup vs baseline: 1.1579x; 1.1579x over previous
//
#include <hip/hip_runtime.h>

#define LAT 128
#define CAP 256   // per-node LDS cache of exp(att); deg>CAP falls back to recompute

// ---------------- projection GEMM v3 ----------------
// Grid (N/64, 3 mats). Per block: stage eL[64][128] once, wL (64k x 128c) twice.
// Thread tile: 4 nodes x 8 cols (cols j0*4..+3 and 64+j0*4..+3).
__global__ __launch_bounds__(256) void proj_kernel(
    const float* __restrict__ A,
    const float* __restrict__ Wq, const float* __restrict__ Wk, const float* __restrict__ Wv,
    float* __restrict__ Cq, float* __restrict__ Ckv,
    int N)
{
  __shared__ float eL[64][132];
  __shared__ float wL[64][132];
  const int t = threadIdx.x;
  const int n0 = blockIdx.x * 64;
  const int mat = blockIdx.y;           // 0=q 1=k 2=v
  const float* W = (mat == 0) ? Wq : (mat == 1) ? Wk : Wv;

  // stage embeds tile 64x128 (coalesced float4) -- once per block
  #pragma unroll
  for (int it = 0; it < 8; ++it) {
    int flat = (it * 256 + t) * 4;
    int n = flat >> 7, kk = flat & 127;
    float4 v = make_float4(0.f, 0.f, 0.f, 0.f);
    if (n0 + n < N) v = *(const float4*)(A + (size_t)(n0 + n) * LAT + kk);
    *(float4*)&eL[n][kk] = v;
  }

  const int nl = t & 15;          // nodes nl, nl+16, nl+32, nl+48
  const int j0 = t >> 4;          // col groups j0*4 and 64+j0*4
  float acc[4][8] = {};

  for (int kt = 0; kt < 2; ++kt) {
    __syncthreads();
    #pragma unroll
    for (int it = 0; it < 8; ++it) {
      int flat = (it * 256 + t) * 4;
      int kk = flat >> 7, c = flat & 127;
      *(float4*)&wL[kk][c] = *(const float4*)(W + (size_t)(kt * 64 + kk) * LAT + c);
    }
    __syncthreads();
    #pragma unroll 2
    for (int kk = 0; kk < 64; kk += 2) {
      float4 wa0 = *(float4*)&wL[kk][j0 * 4];
      float4 wb0 = *(float4*)&wL[kk][64 + j0 * 4];
      float4 wa1 = *(float4*)&wL[kk + 1][j0 * 4];
      float4 wb1 = *(float4*)&wL[kk + 1][64 + j0 * 4];
      #pragma unroll
      for (int i = 0; i < 4; ++i) {
        float2 e = *(float2*)&eL[nl + 16 * i][kt * 64 + kk];
        acc[i][0] += e.x * wa0.x + e.y * wa1.x;
        acc[i][1] += e.x * wa0.y + e.y * wa1.y;
        acc[i][2] += e.x * wa0.z + e.y * wa1.z;
        acc[i][3] += e.x * wa0.w + e.y * wa1.w;
        acc[i][4] += e.x * wb0.x + e.y * wb1.x;
        acc[i][5] += e.x * wb0.y + e.y * wb1.y;
        acc[i][6] += e.x * wb0.z + e.y * wb1.z;
        acc[i][7] += e.x * wb0.w + e.y * wb1.w;
      }
    }
  }

  #pragma unroll
  for (int i = 0; i < 4; ++i) {
    int n = n0 + nl + 16 * i;
    if (n < N) {
      float* C = (mat == 0) ? (Cq + (size_t)n * LAT)
                            : (Ckv + (size_t)n * 256 + (mat == 2 ? 128 : 0));
      *(float4*)(C + j0 * 4)      = make_float4(acc[i][0], acc[i][1], acc[i][2], acc[i][3]);
      *(float4*)(C + 64 + j0 * 4) = make_float4(acc[i][4], acc[i][5], acc[i][6], acc[i][7]);
    }
  }
}

// ---------------- CSR build ----------------
__global__ __launch_bounds__(256) void deg_kernel(const int* __restrict__ rows,
                                                  int* __restrict__ counts, int E) {
  int i = blockIdx.x * 256 + threadIdx.x;
  if (i < E) atomicAdd(&counts[rows[i]], 1);
}

__global__ __launch_bounds__(1024) void scan1_kernel(const int* __restrict__ counts,
                                                     int* __restrict__ starts,
                                                     int* __restrict__ bsums, int N) {
  __shared__ int sh[1024];
  int t = threadIdx.x;
  int i = blockIdx.x * 1024 + t;
  int v = (i < N) ? counts[i] : 0;
  sh[t] = v; __syncthreads();
  for (int off = 1; off < 1024; off <<= 1) {
    int x = (t >= off) ? sh[t - off] : 0;
    __syncthreads();
    sh[t] += x;
    __syncthreads();
  }
  if (i < N) starts[i] = sh[t] - v;
  if (t == 1023) bsums[blockIdx.x] = sh[t];
}

__global__ __launch_bounds__(1024) void scan2_kernel(int* __restrict__ bsums, int nb) {
  __shared__ int sh[1024];
  int t = threadIdx.x;
  int v = (t < nb) ? bsums[t] : 0;
  sh[t] = v; __syncthreads();
  for (int off = 1; off < 1024; off <<= 1) {
    int x = (t >= off) ? sh[t - off] : 0;
    __syncthreads();
    sh[t] += x;
    __syncthreads();
  }
  if (t < nb) bsums[t] = sh[t] - v;
}

__global__ __launch_bounds__(256) void scan3_kernel(int* __restrict__ starts,
                                                    const int* __restrict__ bsums,
                                                    int* __restrict__ cursor, int N) {
  int i = blockIdx.x * 256 + threadIdx.x;
  if (i < N) {
    int s = starts[i] + bsums[i >> 10];
    starts[i] = s;
    cursor[i] = s;
  }
}

__global__ __launch_bounds__(256) void fill_kernel(const int* __restrict__ rows,
                                                   const int* __restrict__ cols,
                                                   int* __restrict__ cursor,
                                                   int* __restrict__ eidx,
                                                   int* __restrict__ ecol, int E) {
  int i = blockIdx.x * 256 + threadIdx.x;
  if (i < E) {
    int p = atomicAdd(&cursor[rows[i]], 1);
    eidx[p] = i;
    ecol[p] = cols[i];
  }
}

// ---------------- fused attention: wave per node, 4 edges/step, fused att-norm ----
// lane = (s,g): s=lane>>4 edge slot, g=lane&15 owns dims g*8..g*8+7 (head g>>2).
// Single pass accumulates denom + sum(ea*v), caches ea in LDS; epilogue writes
// outRes and NORMALIZED outAtt (float4 per edge). No separate norm kernel.
__global__ __launch_bounds__(256) void attn_kernel(
    const float* __restrict__ KV,
    const int* __restrict__ starts, const int* __restrict__ counts,
    const int* __restrict__ eidx, const int* __restrict__ ecol,
    float* __restrict__ outRes,    // in: Q rows (stashed); out: result
    float* __restrict__ outAtt,    // normalized attention [E][4]
    int N)
{
  __shared__ float eaL[4][CAP][4];   // [wave][edge idx][head] -- conflict-free writes
  const int w = threadIdx.x >> 6;
  const int lane = threadIdx.x & 63;
  const int n = blockIdx.x * 4 + w;
  if (n >= N) return;                 // whole-wave exit; no __syncthreads below
  const int g = lane & 15;
  const int s = lane >> 4;
  const int start = starts[n];
  const int deg = counts[n];

  const float4 q0 = *(const float4*)(outRes + (size_t)n * LAT + g * 8);
  const float4 q1 = *(const float4*)(outRes + (size_t)n * LAT + g * 8 + 4);

  float denom = 0.f;
  float acc[8] = {};
  for (int base = 0; base < deg; base += 64) {
    int j = base + lane;
    int c_l = 0;
    if (j < deg) c_l = ecol[start + j];
    int m = deg - base; if (m > 64) m = 64;
    int steps = (m + 3) >> 2;
    #pragma unroll 2
    for (int st = 0; st < steps; ++st) {
      int jj = st * 4 + s;
      int c = __shfl(c_l, jj);
      bool valid = (jj < m);
      const float* kv = KV + (size_t)c * 256;
      float4 k0 = *(const float4*)(kv + g * 8);
      float4 k1 = *(const float4*)(kv + g * 8 + 4);
      float4 v0 = *(const float4*)(kv + 128 + g * 8);
      float4 v1 = *(const float4*)(kv + 128 + g * 8 + 4);
      float p = q0.x * k0.x + q0.y * k0.y + q0.z * k0.z + q0.w * k0.w
              + q1.x * k1.x + q1.y * k1.y + q1.z * k1.z + q1.w * k1.w;
      p += __shfl_xor(p, 1);
      p += __shfl_xor(p, 2);               // head-group dot complete
      p = fminf(fmaxf(p, -10.f), 10.f);
      float ea = valid ? __expf(p) : 0.f;
      denom += ea;
      acc[0] += ea * v0.x; acc[1] += ea * v0.y; acc[2] += ea * v0.z; acc[3] += ea * v0.w;
      acc[4] += ea * v1.x; acc[5] += ea * v1.y; acc[6] += ea * v1.z; acc[7] += ea * v1.w;
      int idx = base + jj;
      if (valid && (g & 3) == 0 && idx < CAP) eaL[w][idx][g >> 2] = ea;
    }
  }
  // cross-slot reduction (bits 4,5)
  denom += __shfl_xor(denom, 16);
  denom += __shfl_xor(denom, 32);
  #pragma unroll
  for (int i = 0; i < 8; ++i) {
    acc[i] += __shfl_xor(acc[i], 16);
    acc[i] += __shfl_xor(acc[i], 32);
  }
  const float rden = 1.f / (denom + 1e-8f);

  if (lane < 16) {
    float4 r0 = make_float4(acc[0] * rden, acc[1] * rden, acc[2] * rden, acc[3] * rden);
    float4 r1 = make_float4(acc[4] * rden, acc[5] * rden, acc[6] * rden, acc[7] * rden);
    *(float4*)(outRes + (size_t)n * LAT + g * 8) = r0;
    *(float4*)(outRes + (size_t)n * LAT + g * 8 + 4) = r1;
  }

  // per-head reciprocal denominators for the float4 att writes
  const float r0 = __shfl(rden, 0);
  const float r1 = __shfl(rden, 4);
  const float r2 = __shfl(rden, 8);
  const float r3 = __shfl(rden, 12);

  // epilogue: normalized att for cached edges (one float4 scatter per edge)
  int capped = deg < CAP ? deg : CAP;
  for (int j = lane; j < capped; j += 64) {
    int e = eidx[start + j];
    float4 a = *(float4*)&eaL[w][j][0];
    a.x *= r0; a.y *= r1; a.z *= r2; a.w *= r3;
    *(float4*)(outAtt + (size_t)e * 4) = a;
  }

  // fallback for deg > CAP (practically never for Poisson(16) degrees)
  const float myr = (g >> 2) == 0 ? r0 : (g >> 2) == 1 ? r1 : (g >> 2) == 2 ? r2 : r3;
  for (int base = CAP; base < deg; base += 64) {
    int j = base + lane;
    int c_l = 0, e_l = 0;
    if (j < deg) { c_l = ecol[start + j]; e_l = eidx[start + j]; }
    int m = deg - base; if (m > 64) m = 64;
    int steps = (m + 3) >> 2;
    for (int st = 0; st < steps; ++st) {
      int jj = st * 4 + s;
      int c = __shfl(c_l, jj);
      int e = __shfl(e_l, jj);
      bool valid = (jj < m);
      const float* kv = KV + (size_t)c * 256;
      float4 k0 = *(const float4*)(kv + g * 8);
      float4 k1 = *(const float4*)(kv + g * 8 + 4);
      float p = q0.x * k0.x + q0.y * k0.y + q0.z * k0.z + q0.w * k0.w
              + q1.x * k1.x + q1.y * k1.y + q1.z * k1.z + q1.w * k1.w;
      p += __shfl_xor(p, 1);
      p += __shfl_xor(p, 2);
      p = fminf(fmaxf(p, -10.f), 10.f);
      float av = __expf(p) * myr;
      int lb = lane & 48;
      float4 o;
      o.x = __shfl(av, lb + 0);
      o.y = __shfl(av, lb + 4);
      o.z = __shfl(av, lb + 8);
      o.w = __shfl(av, lb + 12);
      if (valid && g == 0) *(float4*)(outAtt + (size_t)e * 4) = o;
    }
  }
}

// ---------------- launch ----------------
extern "C" void kernel_launch(void* const* d_in, const int* in_sizes, int n_in,
                              void* d_out, int out_size, void* d_ws, size_t ws_size,
                              hipStream_t stream) {
  const float* embeds = (const float*)d_in[0];
  const float* qT = (const float*)d_in[1];
  const float* kT = (const float*)d_in[2];
  const float* vT = (const float*)d_in[3];
  const int* rows = (const int*)d_in[4];
  const int* cols = (const int*)d_in[5];

  if (in_sizes[1] != LAT * LAT) return;   // kernel specialized for latdim=128
  const int N = in_sizes[0] / LAT;
  const int E = in_sizes[4];

  float* outRes = (float*)d_out;                    // [N,128]; temporarily holds Q
  float* outAtt = outRes + (size_t)N * LAT;         // [E,4]

  // workspace carve-up
  char* w = (char*)d_ws;
  size_t need = (size_t)N * 256 * 4 + (size_t)N * 4 * 3 + 1024 * 4 + (size_t)E * 4 * 2;
  if (ws_size < need) return;
  float* KV = (float*)w;      w += (size_t)N * 256 * 4;   // K|V interleaved rows
  int* counts = (int*)w;      w += (size_t)N * 4;
  int* starts = (int*)w;      w += (size_t)N * 4;
  int* cursor = (int*)w;      w += (size_t)N * 4;
  int* bsums  = (int*)w;      w += 1024 * 4;
  int* eidx   = (int*)w;      w += (size_t)E * 4;
  int* ecol   = (int*)w;      w += (size_t)E * 4;

  hipMemsetAsync(counts, 0, (size_t)N * 4, stream);

  // per-node projections: Q -> outRes (stash), K|V -> interleaved workspace
  dim3 pg((N + 63) / 64, 3);
  proj_kernel<<<pg, 256, 0, stream>>>(embeds, qT, kT, vT, outRes, KV, N);

  // CSR of edges bucketed by destination (rows)
  deg_kernel<<<(E + 255) / 256, 256, 0, stream>>>(rows, counts, E);
  int nb = (N + 1023) / 1024;
  scan1_kernel<<<nb, 1024, 0, stream>>>(counts, starts, bsums, N);
  scan2_kernel<<<1, 1024, 0, stream>>>(bsums, nb);
  scan3_kernel<<<(N + 255) / 256, 256, 0, stream>>>(starts, bsums, cursor, N);
  fill_kernel<<<(E + 255) / 256, 256, 0, stream>>>(rows, cols, cursor, eidx, ecol, E);

  // fused single-pass attention + aggregation + normalization (no atomics)
  attn_kernel<<<(N + 3) / 4, 256, 0, stream>>>(KV, starts, counts, eidx, ecol,
                                               outRes, outAtt, N);
}